// Round 7
// baseline (626.672 us; speedup 1.0000x reference)
//
#include <hip/hip_runtime.h>

// EdgeBlock: out = relu(concat(xn[src], xn[dst], xe) @ W1 + b1) @ W2 + b2
// R7: BM=128/512thr/8waves. A direct-to-register (node: bf16 table gather;
// edge: f32->cvt), ping-pong prefetch. B via global_load_lds, 3-buffer,
// 2-ahead, counted vmcnt + raw s_barrier (T3/T4). Source-swizzled B slots.
// W1->W2 as one 32-chunk pipeline. Hs swizzled; coalesced f32 out via LDS.

typedef __attribute__((ext_vector_type(8))) short short8;
typedef __attribute__((ext_vector_type(4))) float f32x4;
typedef __attribute__((address_space(1))) unsigned int* gp1_t;
typedef __attribute__((address_space(3))) unsigned int* lp3_t;

#define HS_OFF 49152     // Bs: 3 x 16KB, then Hs 64KB
#define SMEM_SZ 114688   // 112KB -> 1 block/CU, 8 waves
#define LDO 260

#define WAITV(N) asm volatile("s_waitcnt vmcnt(" #N ")" ::: "memory")
#define PHASE_SYNC() do { __builtin_amdgcn_s_barrier(); __builtin_amdgcn_sched_barrier(0); } while (0)

__device__ __forceinline__ unsigned short f2b(float f) {
  unsigned int u = __float_as_uint(f);
  return (unsigned short)((u + 0x7FFFu + ((u >> 16) & 1u)) >> 16);
}
__device__ __forceinline__ unsigned int f2b2(float lo, float hi) {
  return (unsigned int)f2b(lo) | ((unsigned int)f2b(hi) << 16);
}
__device__ __forceinline__ void gload16(const void* g, void* l) {
  __builtin_amdgcn_global_load_lds((gp1_t)g, (lp3_t)l, 16, 0, 0);
}

// Pack W[k][256] -> wp[kc][n][slot][j] bf16, chunk=32 k-rows (16KB contiguous).
// Slot rotation (source-side swizzle): slot s at row n holds k-group ((s-(n>>1))&3).
__global__ void prep_w_kernel(const float* __restrict__ w,
                              unsigned short* __restrict__ wp, int total) {
  int i = blockIdx.x * 256 + threadIdx.x;
  if (i >= total) return;
  int kc = i >> 13;            // 8192 elems per chunk
  int rem = i & 8191;
  int n = rem >> 5;
  int within = rem & 31;
  int s = within >> 3;
  int j = within & 7;
  int kin = (((s - (n >> 1)) & 3) << 3) | j;
  wp[i] = f2b(w[(size_t)(kc * 32 + kin) * 256 + n]);
}

__global__ void conv_bf16_kernel(const float* __restrict__ x,
                                 unsigned short* __restrict__ y, int n4) {
  int i = blockIdx.x * 256 + threadIdx.x;
  if (i >= n4) return;
  float4 v = ((const float4*)x)[i];
  ushort4 u;
  u.x = f2b(v.x); u.y = f2b(v.y); u.z = f2b(v.z); u.w = f2b(v.w);
  ((ushort4*)y)[i] = u;
}

__global__ __launch_bounds__(512, 2) void edge_mlp_kernel(
    const float* __restrict__ xnode, const float* __restrict__ xedge,
    const int* __restrict__ eidx,
    const unsigned short* __restrict__ nodeb, int use_nodeb,
    const unsigned short* __restrict__ wt1p, const float* __restrict__ b1,
    const unsigned short* __restrict__ wt2p, const float* __restrict__ b2,
    float* __restrict__ out, int E) {
  __shared__ __align__(16) char smem[SMEM_SZ];
  char* Bs = smem;
  char* Hs = smem + HS_OFF;

  const int t = threadIdx.x, w = t >> 6, l = t & 63;
  const int lr = l & 15, lk = l >> 4;
  const int wr = w >> 2, wc = w & 3;     // 2(M) x 4(N) wave grid
  const int ebase = blockIdx.x * 128;

  int er[4], nsrc[4], ndst[4];
#pragma unroll
  for (int mi = 0; mi < 4; ++mi) {
    int e = ebase + wr * 64 + mi * 16 + lr;
    if (e >= E) e = E - 1;
    er[mi] = e;
    nsrc[mi] = eidx[e];
    ndst[mi] = eidx[E + e];
  }

  f32x4 acc[4][4];
#pragma unroll
  for (int i = 0; i < 4; ++i)
#pragma unroll
    for (int j = 0; j < 4; ++j) acc[i][j] = (f32x4)0.0f;

  // ---- staging / load helpers ----
  auto stageB = [&](const unsigned short* wp, int c, int buf) {
    const char* g = (const char*)wp + (size_t)c * 16384 + t * 16;
    char* lb = Bs + buf * 16384 + (w << 10);   // wave-uniform base, lane*16
    gload16(g, lb);
    gload16(g + 8192, lb + 8192);
  };
  auto stageC = [&](int c) {                   // unified W1/W2 chunk pipeline
    if (c < 24) stageB(wt1p, c, c % 3);
    else        stageB(wt2p, c - 24, c % 3);
  };
  auto loadA_node = [&](int c, short8 (&a)[4]) {   // bf16 gather, 16B/lane/frag
    const int* nid = (c < 8) ? nsrc : ndst;
    const int co = (c & 7) * 64 + lk * 16;
#pragma unroll
    for (int mi = 0; mi < 4; ++mi)
      a[mi] = *(const short8*)((const char*)nodeb + (size_t)nid[mi] * 512 + co);
  };
  auto loadA_f32 = [&](int c, float4 (&m)[4][2]) { // f32 source, cvt later
    const float* base; const int* rows; int co;
    if (c < 8)       { base = xnode; rows = nsrc; co = c * 32 + lk * 8; }
    else if (c < 16) { base = xnode; rows = ndst; co = (c - 8) * 32 + lk * 8; }
    else             { base = xedge; rows = er;   co = (c - 16) * 32 + lk * 8; }
#pragma unroll
    for (int mi = 0; mi < 4; ++mi) {
      const float* p = base + (size_t)rows[mi] * 256 + co;
      m[mi][0] = *(const float4*)p;
      m[mi][1] = *(const float4*)(p + 4);
    }
  };
  auto cvtA = [&](float4 (&m)[4][2], short8 (&a)[4]) {
#pragma unroll
    for (int mi = 0; mi < 4; ++mi) {
      union { short8 s; unsigned int u[4]; } cv;
      cv.u[0] = f2b2(m[mi][0].x, m[mi][0].y);
      cv.u[1] = f2b2(m[mi][0].z, m[mi][0].w);
      cv.u[2] = f2b2(m[mi][1].x, m[mi][1].y);
      cv.u[3] = f2b2(m[mi][1].z, m[mi][1].w);
      a[mi] = cv.s;
    }
  };
  auto loadA = [&](int c, short8 (&a)[4], float4 (&m)[4][2], bool& isf) {
    if (c < 16 && use_nodeb) { loadA_node(c, a); isf = false; }
    else                     { loadA_f32(c, m);  isf = true; }
  };
  auto computeK = [&](int buf, short8 (&a)[4]) {
    short8 bf[4];
    const char* bb = Bs + buf * 16384;
#pragma unroll
    for (int ni = 0; ni < 4; ++ni) {
      const int row = wc * 64 + ni * 16 + lr;
      const int slot = (lk + (row >> 1)) & 3;      // inverse of source swizzle
      bf[ni] = *(const short8*)(bb + row * 64 + slot * 16);
    }
    __builtin_amdgcn_s_setprio(1);
#pragma unroll
    for (int mi = 0; mi < 4; ++mi)
#pragma unroll
      for (int ni = 0; ni < 4; ++ni)
        acc[mi][ni] = __builtin_amdgcn_mfma_f32_16x16x32_bf16(
            a[mi], bf[ni], acc[mi][ni], 0, 0, 0);
    __builtin_amdgcn_s_setprio(0);
  };

  short8 afE[4], afO[4];
  float4 mE[4][2], mO[4][2];
  bool fE = false, fO = false;

  // ---- prologue: 2 chunks in flight + A(0) ----
  stageC(0);
  stageC(1);
  loadA(0, afE, mE, fE);

  // ---- GEMM1 chunks 0..15 (node segments; waits: 2 stage + 4 regA = 6) ----
  for (int tt = 0; tt < 16; tt += 2) {
    WAITV(6);
    PHASE_SYNC();
    stageC(tt + 2);
    loadA(tt + 1, afO, mO, fO);
    if (fE) cvtA(mE, afE);
    computeK(tt % 3, afE);

    WAITV(6);
    PHASE_SYNC();
    stageC(tt + 3);
    loadA(tt + 2, afE, mE, fE);
    if (fO) cvtA(mO, afO);
    computeK((tt + 1) % 3, afO);
  }

  // ---- GEMM1 chunks 16..23 (edge segment; waits: 2 stage + 8 regA = 10) ----
  for (int tt = 16; tt < 24; tt += 2) {
    WAITV(10);
    PHASE_SYNC();
    stageC(tt + 2);
    loadA(tt + 1, afO, mO, fO);
    if (fE) cvtA(mE, afE);
    computeK(tt % 3, afE);

    WAITV(10);
    PHASE_SYNC();
    stageC(tt + 3);                       // tt=22 -> chunk 25 (W2 #1)
    if (tt + 2 < 24) loadA(tt + 2, afE, mE, fE);
    if (fO) cvtA(mO, afO);
    computeK((tt + 1) % 3, afO);
  }

  // ---- bias + ReLU -> Hs (swizzled paired u32 writes); W2 chunks in flight ----
#pragma unroll
  for (int ni = 0; ni < 4; ++ni) {
    const int col = wc * 64 + ni * 16 + lr;
    const float bias = b1[col];
    const int cole = col & ~1;
    const int chunk = cole >> 3;
    const int cb = (cole & 6) * 2;
#pragma unroll
    for (int mi = 0; mi < 4; ++mi) {
      float v[4], p[4];
#pragma unroll
      for (int r = 0; r < 4; ++r) {
        float x = acc[mi][ni][r] + bias;
        v[r] = x > 0.f ? x : 0.f;
        acc[mi][ni][r] = 0.f;
      }
#pragma unroll
      for (int r = 0; r < 4; ++r) p[r] = __shfl_xor(v[r], 1, 64);
      const int r0 = (lr & 1) ? 2 : 0;
#pragma unroll
      for (int rr = 0; rr < 2; ++rr) {
        const int r = r0 + rr;
        const int row = wr * 64 + mi * 16 + lk * 4 + r;
        const float lo = (lr & 1) ? p[r] : v[r];
        const float hi = (lr & 1) ? v[r] : p[r];
        *(unsigned int*)(Hs + row * 512 + ((chunk ^ (row & 7)) << 4) + cb) =
            f2b2(lo, hi);
      }
    }
  }
  asm volatile("s_waitcnt lgkmcnt(0)" ::: "memory");   // Hs writes done pre-barrier

  // ---- GEMM2: 8 chunks (global 24..31), A from Hs ----
#pragma unroll
  for (int u = 0; u < 8; ++u) {
    if (u < 7) { WAITV(2); } else { WAITV(0); }
    PHASE_SYNC();
    if (u < 6) stageB(wt2p, u + 2, (26 + u) % 3);
    short8 af2[4], bf2[4];
    const char* bb = Bs + ((24 + u) % 3) * 16384;
#pragma unroll
    for (int mi = 0; mi < 4; ++mi) {
      const int row = wr * 64 + mi * 16 + lr;
      af2[mi] = *(const short8*)(Hs + row * 512 +
                                 ((((u << 2) + lk) ^ (row & 7)) << 4));
    }
#pragma unroll
    for (int ni = 0; ni < 4; ++ni) {
      const int row = wc * 64 + ni * 16 + lr;
      const int slot = (lk + (row >> 1)) & 3;
      bf2[ni] = *(const short8*)(bb + row * 64 + slot * 16);
    }
    __builtin_amdgcn_s_setprio(1);
#pragma unroll
    for (int mi = 0; mi < 4; ++mi)
#pragma unroll
      for (int ni = 0; ni < 4; ++ni)
        acc[mi][ni] = __builtin_amdgcn_mfma_f32_16x16x32_bf16(
            af2[mi], bf2[ni], acc[mi][ni], 0, 0, 0);
    __builtin_amdgcn_s_setprio(0);
  }

  // ---- bias + coalesced f32 store via LDS round-trip (two 64-row passes) ----
  float* outst = (float*)smem;
#pragma unroll
  for (int p = 0; p < 2; ++p) {
    __syncthreads();
    if (wr == p) {
#pragma unroll
      for (int ni = 0; ni < 4; ++ni) {
        const int col = wc * 64 + ni * 16 + lr;
        const float bias = b2[col];
#pragma unroll
        for (int mi = 0; mi < 4; ++mi)
#pragma unroll
          for (int r = 0; r < 4; ++r)
            outst[(mi * 16 + lk * 4 + r) * LDO + col] = acc[mi][ni][r] + bias;
      }
    }
    __syncthreads();
#pragma unroll
    for (int it = 0; it < 8; ++it) {
      const int idx = it * 2048 + t * 4;
      const int lrow = idx >> 8;
      const int cc = idx & 255;
      const int grow = ebase + p * 64 + lrow;
      if (grow < E)
        *(float4*)(out + (size_t)grow * 256 + cc) =
            *(const float4*)(outst + lrow * LDO + cc);
    }
  }
}

extern "C" void kernel_launch(void* const* d_in, const int* in_sizes, int n_in,
                              void* d_out, int out_size, void* d_ws, size_t ws_size,
                              hipStream_t stream) {
  const float* xnode = (const float*)d_in[0];
  const float* xedge = (const float*)d_in[1];
  const int* eidx = (const int*)d_in[2];
  const float* W1 = (const float*)d_in[3];
  const float* b1 = (const float*)d_in[4];
  const float* W2 = (const float*)d_in[5];
  const float* b2 = (const float*)d_in[6];
  float* out = (float*)d_out;

  const int NN = in_sizes[0] / 256;   // 50000
  const int E = in_sizes[1] / 256;    // 300000

  char* ws = (char*)d_ws;
  unsigned short* wt1p = (unsigned short*)ws;                   // 24 x 16KB
  unsigned short* wt2p = (unsigned short*)(ws + 24 * 16384);    //  8 x 16KB
  unsigned short* nodeb = (unsigned short*)(ws + 32 * 16384);   // NN*512B
  const size_t need = (size_t)32 * 16384 + (size_t)NN * 512;
  const int use_nodeb = (ws_size >= need) ? 1 : 0;

  prep_w_kernel<<<(24 * 8192 + 255) / 256, 256, 0, stream>>>(W1, wt1p, 24 * 8192);
  prep_w_kernel<<<(8 * 8192 + 255) / 256, 256, 0, stream>>>(W2, wt2p, 8 * 8192);
  if (use_nodeb) {
    const int n4 = NN * 64;
    conv_bf16_kernel<<<(n4 + 255) / 256, 256, 0, stream>>>(xnode, nodeb, n4);
  }

  edge_mlp_kernel<<<(E + 127) / 128, 512, 0, stream>>>(
      xnode, xedge, eidx, nodeb, use_nodeb, wt1p, b1, wt2p, b2, out, E);
}

// Round 8
// 381.736 us; speedup vs baseline: 1.6416x; 1.6416x over previous
//
#include <hip/hip_runtime.h>

// EdgeBlock: out = relu(concat(xn[src], xn[dst], xe) @ W1 + b1) @ W2 + b2
// R8: BM=128/512thr/8waves. ALL staging via global_load_lds (block-cooperative):
// B from pre-packed slot-swizzled weights, A-node from bf16 table with
// pre-swizzled per-lane source addresses, A-edge via T14 reg-stage (parity-
// unrolled sets). 3-buffer/2-ahead counted vmcnt + raw s_barrier, single
// 32-chunk W1->W2 pipeline. No sched pinning. Fallback drain kernel for tiny ws.

typedef __attribute__((ext_vector_type(8))) short short8;
typedef __attribute__((ext_vector_type(4))) float f32x4;
typedef __attribute__((address_space(1))) unsigned int* gp1_t;
typedef __attribute__((address_space(3))) unsigned int* lp3_t;

#define WAITV(N) asm volatile("s_waitcnt vmcnt(" #N ")" ::: "memory")
#define WAITL0   asm volatile("s_waitcnt lgkmcnt(0)" ::: "memory")
#define BAR()    __builtin_amdgcn_s_barrier()

// full-kernel LDS map
#define AS_OFF 0          // As: 3 x 8KB
#define BS_OFF 24576      // Bs: 3 x 16KB
#define HS_OFF 73728      // Hs: 64KB
#define SMEM_SZ 139264    // 136KB -> 1 block/CU
#define LDO 260

__device__ __forceinline__ unsigned short f2b(float f) {
  unsigned int u = __float_as_uint(f);
  return (unsigned short)((u + 0x7FFFu + ((u >> 16) & 1u)) >> 16);
}
__device__ __forceinline__ unsigned int f2b2(float lo, float hi) {
  return (unsigned int)f2b(lo) | ((unsigned int)f2b(hi) << 16);
}
__device__ __forceinline__ void gload16(const void* g, void* l) {
  __builtin_amdgcn_global_load_lds((gp1_t)g, (lp3_t)l, 16, 0, 0);
}

// Pack W[k][256] -> wp[kc][n][s][j], chunk kc = 32 k-rows (16KB). Slot s at
// row n holds k-group ((s-(n>>1))&3) (bank-conflict-free frag reads).
__global__ void prep_w_kernel(const float* __restrict__ w,
                              unsigned short* __restrict__ wp, int total) {
  int i = blockIdx.x * 256 + threadIdx.x;
  if (i >= total) return;
  int kc = i >> 13;
  int rem = i & 8191;
  int n = rem >> 5;
  int s = (rem >> 3) & 3;
  int j = rem & 7;
  int kin = (((s - (n >> 1)) & 3) << 3) | j;
  wp[i] = f2b(w[(size_t)(kc * 32 + kin) * 256 + n]);
}

__global__ void conv_bf16_kernel(const float* __restrict__ x,
                                 unsigned short* __restrict__ y, int n4) {
  int i = blockIdx.x * 256 + threadIdx.x;
  if (i >= n4) return;
  float4 v = ((const float4*)x)[i];
  ushort4 u;
  u.x = f2b(v.x); u.y = f2b(v.y); u.z = f2b(v.z); u.w = f2b(v.w);
  ((ushort4*)y)[i] = u;
}

__global__ __launch_bounds__(512, 2) void edge_mlp_full(
    const float* __restrict__ xedge, const int* __restrict__ eidx,
    const unsigned short* __restrict__ nodeb,
    const unsigned short* __restrict__ wt1p, const float* __restrict__ b1,
    const unsigned short* __restrict__ wt2p, const float* __restrict__ b2,
    float* __restrict__ out, int E) {
  __shared__ __align__(16) char smem[SMEM_SZ];
  char* As = smem + AS_OFF;
  char* Bs = smem + BS_OFF;
  char* Hs = smem + HS_OFF;

  const int t = threadIdx.x, w = t >> 6, l = t & 63;
  const int lr = l & 15, lk = l >> 4;
  const int wr = w >> 2, wc = w & 3;       // 2(M) x 4(N) wave grid
  const int row4 = t >> 2, c4 = t & 3;     // staging row 0..127, 16B slot
  const int ebase = blockIdx.x * 128;

  int e = ebase + row4;
  if (e >= E) e = E - 1;
  const int isrc = eidx[e], idst = eidx[E + e];
  const int swg = (c4 - (row4 >> 1)) & 3;  // source k-group for linear slot c4

  f32x4 acc[4][4];
#pragma unroll
  for (int i = 0; i < 4; ++i)
#pragma unroll
    for (int j = 0; j < 4; ++j) acc[i][j] = (f32x4)0.0f;

  auto stageB = [&](const unsigned short* wp, int c, int buf) {
    const char* g = (const char*)wp + (size_t)c * 16384 + t * 16;
    char* lb = Bs + buf * 16384 + (w << 10);
    gload16(g, lb);
    gload16(g + 8192, lb + 8192);
  };
  auto gloadA = [&](int c, int buf) {       // node chunks (c<16), swizzled src
    const int nid = (c < 8) ? isrc : idst;
    const char* g = (const char*)nodeb + (size_t)nid * 512 + (c & 7) * 64 + swg * 16;
    gload16(g, As + buf * 8192 + (w << 10));
  };
  auto edge_issue = [&](int c, float4& a, float4& b) {
    const float* p = xedge + (size_t)e * 256 + (c - 16) * 32 + c4 * 8;
    a = ((const float4*)p)[0];
    b = ((const float4*)p)[1];
  };
  auto edge_write = [&](int c, const float4& a, const float4& b) {
    uint4 u;
    u.x = f2b2(a.x, a.y); u.y = f2b2(a.z, a.w);
    u.z = f2b2(b.x, b.y); u.w = f2b2(b.z, b.w);
    const int sw = (c4 + (row4 >> 1)) & 3;
    *(uint4*)(As + (c % 3) * 8192 + row4 * 64 + sw * 16) = u;
  };
  auto fragsA = [&](int buf, short8 (&af)[4]) {
#pragma unroll
    for (int mi = 0; mi < 4; ++mi) {
      const int row = wr * 64 + mi * 16 + lr;
      const int slot = (lk + (row >> 1)) & 3;
      af[mi] = *(const short8*)(As + buf * 8192 + row * 64 + slot * 16);
    }
  };
  auto fragsB = [&](int buf, short8 (&bf)[4]) {
#pragma unroll
    for (int ni = 0; ni < 4; ++ni) {
      const int row = wc * 64 + ni * 16 + lr;
      const int slot = (lk + (row >> 1)) & 3;
      bf[ni] = *(const short8*)(Bs + buf * 16384 + row * 64 + slot * 16);
    }
  };
  auto domfma = [&](short8 (&af)[4], short8 (&bf)[4]) {
    __builtin_amdgcn_s_setprio(1);
#pragma unroll
    for (int mi = 0; mi < 4; ++mi)
#pragma unroll
      for (int ni = 0; ni < 4; ++ni)
        acc[mi][ni] = __builtin_amdgcn_mfma_f32_16x16x32_bf16(
            af[mi], bf[ni], acc[mi][ni], 0, 0, 0);
    __builtin_amdgcn_s_setprio(0);
  };

  short8 af[4], bf[4];
  float4 eA0, eA1, eB0, eB1;               // edge reg sets (even/odd chunks)

  // ---- prologue: chunks 0,1 in flight ----
  stageB(wt1p, 0, 0); gloadA(0, 0);
  stageB(wt1p, 1, 1); gloadA(1, 1);

  // ---- chunks 0..13 (node; stage k+2 = node) ----
  for (int k = 0; k < 14; ++k) {
    WAITV(3);
    BAR();
    fragsA(k % 3, af); fragsB(k % 3, bf);
    stageB(wt1p, k + 2, (k + 2) % 3);
    gloadA(k + 2, (k + 2) % 3);
    domfma(af, bf);
  }
  // ---- chunk 14: stage 16 = first edge (set A) ----
  {
    WAITV(3);
    BAR();
    fragsA(2, af); fragsB(2, bf);          // 14%3 = 2
    stageB(wt1p, 16, 1);                   // 16%3 = 1
    edge_issue(16, eA0, eA1);
    domfma(af, bf);
  }
  // ---- chunks 15..22 (pairs; T14 write-late; parity-static reg sets) ----
  for (int kk = 15; kk < 23; kk += 2) {
    // k = kk (odd): read kk; stage kk+2 (odd -> set B); write kk+1 (set A)
    WAITV(4);
    BAR();
    fragsA(kk % 3, af); fragsB(kk % 3, bf);
    stageB(wt1p, kk + 2, (kk + 2) % 3);
    edge_issue(kk + 2, eB0, eB1);
    domfma(af, bf);
    edge_write(kk + 1, eA0, eA1);
    WAITL0;
    // k = kk+1 (even): read kk+1; stage kk+3 (even -> set A); write kk+2 (set B)
    WAITV(4);
    BAR();
    fragsA((kk + 1) % 3, af); fragsB((kk + 1) % 3, bf);
    if (kk + 3 < 24) {
      stageB(wt1p, kk + 3, (kk + 3) % 3);
      edge_issue(kk + 3, eA0, eA1);
    } else {
      stageB(wt2p, 0, 0);                  // kk=21: chunk 24 (W2 #0), 24%3=0
    }
    domfma(af, bf);
    edge_write(kk + 2, eB0, eB1);
    WAITL0;
  }
  // ---- chunk 23 ----
  {
    WAITV(2);
    BAR();
    fragsA(2, af); fragsB(2, bf);          // 23%3 = 2
    stageB(wt2p, 1, 1);                    // chunk 25, 25%3 = 1
    domfma(af, bf);
  }

  // ---- bias + ReLU -> Hs (swizzled paired u32 writes) ----
#pragma unroll
  for (int ni = 0; ni < 4; ++ni) {
    const int col = wc * 64 + ni * 16 + lr;
    const float bias = b1[col];
    const int cole = col & ~1;
    const int chunk = cole >> 3;
    const int cb = (cole & 6) * 2;
#pragma unroll
    for (int mi = 0; mi < 4; ++mi) {
      float v[4], p[4];
#pragma unroll
      for (int r = 0; r < 4; ++r) {
        float x = acc[mi][ni][r] + bias;
        v[r] = x > 0.f ? x : 0.f;
        acc[mi][ni][r] = 0.f;
      }
#pragma unroll
      for (int r = 0; r < 4; ++r) p[r] = __shfl_xor(v[r], 1, 64);
      const int r0 = (lr & 1) ? 2 : 0;
#pragma unroll
      for (int rr = 0; rr < 2; ++rr) {
        const int r = r0 + rr;
        const int row = wr * 64 + mi * 16 + lk * 4 + r;
        const float lo = (lr & 1) ? p[r] : v[r];
        const float hi = (lr & 1) ? v[r] : p[r];
        *(unsigned int*)(Hs + row * 512 + ((chunk ^ (row & 7)) << 4) + cb) =
            f2b2(lo, hi);
      }
    }
  }
  WAITL0;   // Hs writes landed (cross-wave readiness via next barrier)

  // ---- GEMM2: chunks 24..31, A from Hs, B pipeline continues ----
#pragma unroll
  for (int u = 0; u < 8; ++u) {
    if (u < 7) { WAITV(2); } else { WAITV(0); }
    BAR();
    short8 af2[4], bf2[4];
#pragma unroll
    for (int mi = 0; mi < 4; ++mi) {
      const int row = wr * 64 + mi * 16 + lr;
      af2[mi] = *(const short8*)(Hs + row * 512 +
                                 ((((u << 2) + lk) ^ (row & 7)) << 4));
    }
    fragsB((24 + u) % 3, bf2);
    if (u < 6) stageB(wt2p, u + 2, (26 + u) % 3);
    domfma(af2, bf2);
  }

  // ---- bias + coalesced f32 store via LDS (two 64-row passes) ----
  float* outst = (float*)smem;
#pragma unroll
  for (int p = 0; p < 2; ++p) {
    __syncthreads();
    if (wr == p) {
#pragma unroll
      for (int ni = 0; ni < 4; ++ni) {
        const int col = wc * 64 + ni * 16 + lr;
        const float bias = b2[col];
#pragma unroll
        for (int mi = 0; mi < 4; ++mi)
#pragma unroll
          for (int r = 0; r < 4; ++r)
            outst[(mi * 16 + lk * 4 + r) * LDO + col] = acc[mi][ni][r] + bias;
      }
    }
    __syncthreads();
#pragma unroll
    for (int it = 0; it < 8; ++it) {
      const int idx = it * 2048 + t * 4;
      const int lrow = idx >> 8;
      const int cc = idx & 255;
      const int grow = ebase + p * 64 + lrow;
      if (grow < E)
        *(float4*)(out + (size_t)grow * 256 + cc) =
            *(const float4*)(outst + lrow * LDO + cc);
    }
  }
}

// Fallback (tiny ws): single-buffer, __syncthreads-drained, manual A staging.
__global__ __launch_bounds__(512, 2) void edge_mlp_simple(
    const float* __restrict__ xnode, const float* __restrict__ xedge,
    const int* __restrict__ eidx,
    const unsigned short* __restrict__ wt1p, const float* __restrict__ b1,
    const unsigned short* __restrict__ wt2p, const float* __restrict__ b2,
    float* __restrict__ out, int E) {
  __shared__ __align__(16) char smem[90112];  // As 8K @0, Bs 16K @8192, Hs 64K @24576
  char* As = smem;
  char* Bs = smem + 8192;
  char* Hs = smem + 24576;

  const int t = threadIdx.x, w = t >> 6, l = t & 63;
  const int lr = l & 15, lk = l >> 4;
  const int wr = w >> 2, wc = w & 3;
  const int row4 = t >> 2, c4 = t & 3;
  const int ebase = blockIdx.x * 128;
  int e = ebase + row4;
  if (e >= E) e = E - 1;
  const int isrc = eidx[e], idst = eidx[E + e];

  f32x4 acc[4][4];
#pragma unroll
  for (int i = 0; i < 4; ++i)
#pragma unroll
    for (int j = 0; j < 4; ++j) acc[i][j] = (f32x4)0.0f;

  auto stageB1 = [&](const unsigned short* wp, int c) {
    const char* g = (const char*)wp + (size_t)c * 16384 + t * 16;
    char* lb = Bs + (w << 10);
    gload16(g, lb);
    gload16(g + 8192, lb + 8192);
  };
  auto mfma16 = [&](short8 (&af)[4], short8 (&bf)[4]) {
#pragma unroll
    for (int mi = 0; mi < 4; ++mi)
#pragma unroll
      for (int ni = 0; ni < 4; ++ni)
        acc[mi][ni] = __builtin_amdgcn_mfma_f32_16x16x32_bf16(
            af[mi], bf[ni], acc[mi][ni], 0, 0, 0);
  };

  for (int c = 0; c < 24; ++c) {
    stageB1(wt1p, c);
    const float* p = ((c < 8) ? xnode + (size_t)isrc * 256
                              : (c < 16) ? xnode + (size_t)idst * 256
                                         : xedge + (size_t)e * 256) +
                     (c & 7) * 32 + c4 * 8;
    float4 a = ((const float4*)p)[0], b = ((const float4*)p)[1];
    uint4 u;
    u.x = f2b2(a.x, a.y); u.y = f2b2(a.z, a.w);
    u.z = f2b2(b.x, b.y); u.w = f2b2(b.z, b.w);
    const int sw = (c4 + (row4 >> 1)) & 3;
    *(uint4*)(As + row4 * 64 + sw * 16) = u;
    __syncthreads();
    short8 af[4], bf[4];
#pragma unroll
    for (int mi = 0; mi < 4; ++mi) {
      const int row = wr * 64 + mi * 16 + lr;
      const int slot = (lk + (row >> 1)) & 3;
      af[mi] = *(const short8*)(As + row * 64 + slot * 16);
    }
#pragma unroll
    for (int ni = 0; ni < 4; ++ni) {
      const int row = wc * 64 + ni * 16 + lr;
      const int slot = (lk + (row >> 1)) & 3;
      bf[ni] = *(const short8*)(Bs + row * 64 + slot * 16);
    }
    mfma16(af, bf);
    __syncthreads();
  }

#pragma unroll
  for (int ni = 0; ni < 4; ++ni) {
    const int col = wc * 64 + ni * 16 + lr;
    const float bias = b1[col];
#pragma unroll
    for (int mi = 0; mi < 4; ++mi)
#pragma unroll
      for (int r = 0; r < 4; ++r) {
        float x = acc[mi][ni][r] + bias;
        x = x > 0.f ? x : 0.f;
        const int row = wr * 64 + mi * 16 + lk * 4 + r;
        *(unsigned short*)(Hs + row * 512 + ((col >> 3) ^ (row & 7)) * 16 +
                           (col & 7) * 2) = f2b(x);
        acc[mi][ni][r] = 0.f;
      }
  }
  __syncthreads();

  for (int u = 0; u < 8; ++u) {
    stageB1(wt2p, u);
    __syncthreads();
    short8 af[4], bf[4];
#pragma unroll
    for (int mi = 0; mi < 4; ++mi) {
      const int row = wr * 64 + mi * 16 + lr;
      af[mi] = *(const short8*)(Hs + row * 512 +
                                ((((u << 2) + lk) ^ (row & 7)) << 4));
    }
#pragma unroll
    for (int ni = 0; ni < 4; ++ni) {
      const int row = wc * 64 + ni * 16 + lr;
      const int slot = (lk + (row >> 1)) & 3;
      bf[ni] = *(const short8*)(Bs + row * 64 + slot * 16);
    }
    mfma16(af, bf);
    __syncthreads();
  }

  float* outst = (float*)smem;   // 66.5KB < 88KB
#pragma unroll
  for (int p = 0; p < 2; ++p) {
    __syncthreads();
    if (wr == p) {
#pragma unroll
      for (int ni = 0; ni < 4; ++ni) {
        const int col = wc * 64 + ni * 16 + lr;
        const float bias = b2[col];
#pragma unroll
        for (int mi = 0; mi < 4; ++mi)
#pragma unroll
          for (int r = 0; r < 4; ++r)
            outst[(mi * 16 + lk * 4 + r) * LDO + col] = acc[mi][ni][r] + bias;
      }
    }
    __syncthreads();
#pragma unroll
    for (int it = 0; it < 8; ++it) {
      const int idx = it * 2048 + t * 4;
      const int lrow = idx >> 8;
      const int cc = idx & 255;
      const int grow = ebase + p * 64 + lrow;
      if (grow < E)
        *(float4*)(out + (size_t)grow * 256 + cc) =
            *(const float4*)(outst + lrow * LDO + cc);
    }
  }
}

extern "C" void kernel_launch(void* const* d_in, const int* in_sizes, int n_in,
                              void* d_out, int out_size, void* d_ws, size_t ws_size,
                              hipStream_t stream) {
  const float* xnode = (const float*)d_in[0];
  const float* xedge = (const float*)d_in[1];
  const int* eidx = (const int*)d_in[2];
  const float* W1 = (const float*)d_in[3];
  const float* b1 = (const float*)d_in[4];
  const float* W2 = (const float*)d_in[5];
  const float* b2 = (const float*)d_in[6];
  float* out = (float*)d_out;

  const int NN = in_sizes[0] / 256;   // 50000
  const int E = in_sizes[1] / 256;    // 300000

  char* ws = (char*)d_ws;
  unsigned short* wt1p = (unsigned short*)ws;                   // 24 x 16KB
  unsigned short* wt2p = (unsigned short*)(ws + 24 * 16384);    //  8 x 16KB
  unsigned short* nodeb = (unsigned short*)(ws + 32 * 16384);   // NN*512B
  const size_t need_full = (size_t)32 * 16384 + (size_t)NN * 512;

  prep_w_kernel<<<(24 * 8192 + 255) / 256, 256, 0, stream>>>(W1, wt1p, 24 * 8192);
  prep_w_kernel<<<(8 * 8192 + 255) / 256, 256, 0, stream>>>(W2, wt2p, 8 * 8192);

  const int grid = (E + 127) / 128;
  if (ws_size >= need_full) {
    const int n4 = NN * 64;
    conv_bf16_kernel<<<(n4 + 255) / 256, 256, 0, stream>>>(xnode, nodeb, n4);
    edge_mlp_full<<<grid, 512, 0, stream>>>(xedge, eidx, nodeb, wt1p, b1,
                                            wt2p, b2, out, E);
  } else {
    edge_mlp_simple<<<grid, 512, 0, stream>>>(xnode, xedge, eidx, wt1p, b1,
                                              wt2p, b2, out, E);
  }
}

// Round 9
// 361.384 us; speedup vs baseline: 1.7341x; 1.0563x over previous
//
#include <hip/hip_runtime.h>

// EdgeBlock: out = relu(concat(xn[src], xn[dst], xe) @ W1 + b1) @ W2 + b2
// R9: occupancy + decoupling. B-fragments DIRECT global->VGPR from packed
// bf16 weights (no LDS, no barrier coupling, L2-hot). LDS only: As 2x8KB
// dbuf + Hs 64KB (aliased over As after GEMM1) = 65KB -> 2 blocks/CU,
// 16 waves (50% occ). Plain __syncthreads phases; GEMM2 barrier-free.
// A-source swizzle / prep_w slot pack / Hs XOR kept verbatim from R8.

typedef __attribute__((ext_vector_type(8))) short short8;
typedef __attribute__((ext_vector_type(4))) float f32x4;
typedef __attribute__((address_space(1))) unsigned int* gp1_t;
typedef __attribute__((address_space(3))) unsigned int* lp3_t;

#define SMEM_SZ 66560   // max(As 16KB, Hs 64KB, outst 66.5KB) -> 2 blocks/CU
#define LDO 260

__device__ __forceinline__ unsigned short f2b(float f) {
  unsigned int u = __float_as_uint(f);
  return (unsigned short)((u + 0x7FFFu + ((u >> 16) & 1u)) >> 16);
}
__device__ __forceinline__ unsigned int f2b2(float lo, float hi) {
  return (unsigned int)f2b(lo) | ((unsigned int)f2b(hi) << 16);
}
__device__ __forceinline__ void gload16(const void* g, void* l) {
  __builtin_amdgcn_global_load_lds((gp1_t)g, (lp3_t)l, 16, 0, 0);
}

// Pack W[k][256] -> wp[kc][n][s][j], chunk kc = 32 k-rows (16KB). Slot s at
// row n holds k-group ((s-(n>>1))&3). (R8-verified.)
__global__ void prep_w_kernel(const float* __restrict__ w,
                              unsigned short* __restrict__ wp, int total) {
  int i = blockIdx.x * 256 + threadIdx.x;
  if (i >= total) return;
  int kc = i >> 13;
  int rem = i & 8191;
  int n = rem >> 5;
  int s = (rem >> 3) & 3;
  int j = rem & 7;
  int kin = (((s - (n >> 1)) & 3) << 3) | j;
  wp[i] = f2b(w[(size_t)(kc * 32 + kin) * 256 + n]);
}

__global__ void conv_bf16_kernel(const float* __restrict__ x,
                                 unsigned short* __restrict__ y, int n4) {
  int i = blockIdx.x * 256 + threadIdx.x;
  if (i >= n4) return;
  float4 v = ((const float4*)x)[i];
  ushort4 u;
  u.x = f2b(v.x); u.y = f2b(v.y); u.z = f2b(v.z); u.w = f2b(v.w);
  ((ushort4*)y)[i] = u;
}

__global__ __launch_bounds__(512, 4) void edge_mlp_full(
    const float* __restrict__ xedge, const int* __restrict__ eidx,
    const unsigned short* __restrict__ nodeb,
    const unsigned short* __restrict__ wt1p, const float* __restrict__ b1,
    const unsigned short* __restrict__ wt2p, const float* __restrict__ b2,
    float* __restrict__ out, int E) {
  __shared__ __align__(16) char smem[SMEM_SZ];
  char* As = smem;            // 2 x 8KB, dead after GEMM1
  char* Hs = smem;            // 64KB, aliases As (used after GEMM1)

  const int t = threadIdx.x, w = t >> 6, l = t & 63;
  const int lr = l & 15, lk = l >> 4;
  const int wr = w >> 2, wc = w & 3;       // 2(M) x 4(N) wave grid
  const int row4 = t >> 2, c4 = t & 3;     // staging row 0..127, 16B slot
  const int ebase = blockIdx.x * 128;

  int e = ebase + row4;
  if (e >= E) e = E - 1;
  const int isrc = eidx[e], idst = eidx[E + e];
  const int swg = (c4 - (row4 >> 1)) & 3;  // source k-group for linear slot c4

  // loop-invariant per-lane fragment byte-offsets (within a 16KB chunk)
  int aoff[4], boff[4];
#pragma unroll
  for (int mi = 0; mi < 4; ++mi) {
    const int row = wr * 64 + mi * 16 + lr;
    aoff[mi] = row * 64 + (((lk + (row >> 1)) & 3) << 4);
  }
#pragma unroll
  for (int ni = 0; ni < 4; ++ni) {
    const int row = wc * 64 + ni * 16 + lr;
    boff[ni] = row * 64 + (((lk + (row >> 1)) & 3) << 4);
  }

  f32x4 acc[4][4];
#pragma unroll
  for (int i = 0; i < 4; ++i)
#pragma unroll
    for (int j = 0; j < 4; ++j) acc[i][j] = (f32x4)0.0f;

  auto gloadA = [&](int c, int buf) {       // node chunks (c<16), swizzled src
    const int nid = (c < 8) ? isrc : idst;
    const char* g = (const char*)nodeb + (size_t)nid * 512 + (c & 7) * 64 + swg * 16;
    gload16(g, As + buf * 8192 + (w << 10));
  };

  // ---- GEMM1: 24 K-chunks, As double-buffered, B direct-to-VGPR ----
  gloadA(0, 0);
  __syncthreads();

  for (int k = 0; k < 24; ++k) {
    const int buf = k & 1, nb = buf ^ 1;
    const int c = k + 1;
    float4 m0, m1;
    if (c < 16) {
      gloadA(c, nb);
    } else if (c < 24) {                    // edge chunk: issue early (T14)
      const float* p = xedge + (size_t)e * 256 + (c - 16) * 32 + c4 * 8;
      m0 = ((const float4*)p)[0];
      m1 = ((const float4*)p)[1];
    }
    short8 af[4], bf[4];
    const char* ab = As + buf * 8192;
    const char* wb = (const char*)wt1p + k * 16384;
#pragma unroll
    for (int mi = 0; mi < 4; ++mi) af[mi] = *(const short8*)(ab + aoff[mi]);
#pragma unroll
    for (int ni = 0; ni < 4; ++ni) bf[ni] = *(const short8*)(wb + boff[ni]);
    __builtin_amdgcn_s_setprio(1);
#pragma unroll
    for (int mi = 0; mi < 4; ++mi)
#pragma unroll
      for (int ni = 0; ni < 4; ++ni)
        acc[mi][ni] = __builtin_amdgcn_mfma_f32_16x16x32_bf16(
            af[mi], bf[ni], acc[mi][ni], 0, 0, 0);
    __builtin_amdgcn_s_setprio(0);
    if (c >= 16 && c < 24) {                // convert + write late
      uint4 u;
      u.x = f2b2(m0.x, m0.y); u.y = f2b2(m0.z, m0.w);
      u.z = f2b2(m1.x, m1.y); u.w = f2b2(m1.z, m1.w);
      const int sw = (c4 + (row4 >> 1)) & 3;
      *(uint4*)(As + nb * 8192 + row4 * 64 + sw * 16) = u;
    }
    __syncthreads();
  }

  // ---- bias + ReLU -> Hs (XOR-swizzled paired u32 writes; Hs aliases As) ----
#pragma unroll
  for (int ni = 0; ni < 4; ++ni) {
    const int col = wc * 64 + ni * 16 + lr;
    const float bias = b1[col];
    const int cole = col & ~1;
    const int chunk = cole >> 3;
    const int cb = (cole & 6) * 2;
#pragma unroll
    for (int mi = 0; mi < 4; ++mi) {
      float v[4], p[4];
#pragma unroll
      for (int r = 0; r < 4; ++r) {
        float x = acc[mi][ni][r] + bias;
        v[r] = x > 0.f ? x : 0.f;
        acc[mi][ni][r] = 0.f;
      }
#pragma unroll
      for (int r = 0; r < 4; ++r) p[r] = __shfl_xor(v[r], 1, 64);
      const int r0 = (lr & 1) ? 2 : 0;
#pragma unroll
      for (int rr = 0; rr < 2; ++rr) {
        const int r = r0 + rr;
        const int row = wr * 64 + mi * 16 + lk * 4 + r;
        const float lo = (lr & 1) ? p[r] : v[r];
        const float hi = (lr & 1) ? v[r] : p[r];
        *(unsigned int*)(Hs + row * 512 + ((chunk ^ (row & 7)) << 4) + cb) =
            f2b2(lo, hi);
      }
    }
  }
  __syncthreads();

  // ---- GEMM2: 8 chunks, barrier-free; A from Hs, B direct-to-VGPR ----
#pragma unroll
  for (int u = 0; u < 8; ++u) {
    short8 af2[4], bf2[4];
    const char* wb = (const char*)wt2p + u * 16384;
#pragma unroll
    for (int mi = 0; mi < 4; ++mi) {
      const int row = wr * 64 + mi * 16 + lr;
      af2[mi] = *(const short8*)(Hs + row * 512 +
                                 ((((u << 2) + lk) ^ (row & 7)) << 4));
    }
#pragma unroll
    for (int ni = 0; ni < 4; ++ni) bf2[ni] = *(const short8*)(wb + boff[ni]);
    __builtin_amdgcn_s_setprio(1);
#pragma unroll
    for (int mi = 0; mi < 4; ++mi)
#pragma unroll
      for (int ni = 0; ni < 4; ++ni)
        acc[mi][ni] = __builtin_amdgcn_mfma_f32_16x16x32_bf16(
            af2[mi], bf2[ni], acc[mi][ni], 0, 0, 0);
    __builtin_amdgcn_s_setprio(0);
  }

  // ---- bias + coalesced f32 store via LDS (two 64-row passes) ----
  float* outst = (float*)smem;
#pragma unroll
  for (int p = 0; p < 2; ++p) {
    __syncthreads();
    if (wr == p) {
#pragma unroll
      for (int ni = 0; ni < 4; ++ni) {
        const int col = wc * 64 + ni * 16 + lr;
        const float bias = b2[col];
#pragma unroll
        for (int mi = 0; mi < 4; ++mi)
#pragma unroll
          for (int r = 0; r < 4; ++r)
            outst[(mi * 16 + lk * 4 + r) * LDO + col] = acc[mi][ni][r] + bias;
      }
    }
    __syncthreads();
#pragma unroll
    for (int it = 0; it < 8; ++it) {
      const int idx = it * 2048 + t * 4;
      const int lrow = idx >> 8;
      const int cc = idx & 255;
      const int grow = ebase + p * 64 + lrow;
      if (grow < E)
        *(float4*)(out + (size_t)grow * 256 + cc) =
            *(const float4*)(outst + lrow * LDO + cc);
    }
  }
}

// Fallback (tiny ws): single-buffer, __syncthreads-drained, manual A staging.
__global__ __launch_bounds__(512, 2) void edge_mlp_simple(
    const float* __restrict__ xnode, const float* __restrict__ xedge,
    const int* __restrict__ eidx,
    const unsigned short* __restrict__ wt1p, const float* __restrict__ b1,
    const unsigned short* __restrict__ wt2p, const float* __restrict__ b2,
    float* __restrict__ out, int E) {
  __shared__ __align__(16) char smem[90112];
  char* As = smem;
  char* Bs = smem + 8192;
  char* Hs = smem + 24576;

  const int t = threadIdx.x, w = t >> 6, l = t & 63;
  const int lr = l & 15, lk = l >> 4;
  const int wr = w >> 2, wc = w & 3;
  const int row4 = t >> 2, c4 = t & 3;
  const int ebase = blockIdx.x * 128;
  int e = ebase + row4;
  if (e >= E) e = E - 1;
  const int isrc = eidx[e], idst = eidx[E + e];

  f32x4 acc[4][4];
#pragma unroll
  for (int i = 0; i < 4; ++i)
#pragma unroll
    for (int j = 0; j < 4; ++j) acc[i][j] = (f32x4)0.0f;

  auto stageB1 = [&](const unsigned short* wp, int c) {
    const char* g = (const char*)wp + (size_t)c * 16384 + t * 16;
    char* lb = Bs + (w << 10);
    gload16(g, lb);
    gload16(g + 8192, lb + 8192);
  };
  auto mfma16 = [&](short8 (&af)[4], short8 (&bf)[4]) {
#pragma unroll
    for (int mi = 0; mi < 4; ++mi)
#pragma unroll
      for (int ni = 0; ni < 4; ++ni)
        acc[mi][ni] = __builtin_amdgcn_mfma_f32_16x16x32_bf16(
            af[mi], bf[ni], acc[mi][ni], 0, 0, 0);
  };

  for (int c = 0; c < 24; ++c) {
    stageB1(wt1p, c);
    const float* p = ((c < 8) ? xnode + (size_t)isrc * 256
                              : (c < 16) ? xnode + (size_t)idst * 256
                                         : xedge + (size_t)e * 256) +
                     (c & 7) * 32 + c4 * 8;
    float4 a = ((const float4*)p)[0], b = ((const float4*)p)[1];
    uint4 u;
    u.x = f2b2(a.x, a.y); u.y = f2b2(a.z, a.w);
    u.z = f2b2(b.x, b.y); u.w = f2b2(b.z, b.w);
    const int sw = (c4 + (row4 >> 1)) & 3;
    *(uint4*)(As + row4 * 64 + sw * 16) = u;
    __syncthreads();
    short8 af[4], bf[4];
#pragma unroll
    for (int mi = 0; mi < 4; ++mi) {
      const int row = wr * 64 + mi * 16 + lr;
      const int slot = (lk + (row >> 1)) & 3;
      af[mi] = *(const short8*)(As + row * 64 + slot * 16);
    }
#pragma unroll
    for (int ni = 0; ni < 4; ++ni) {
      const int row = wc * 64 + ni * 16 + lr;
      const int slot = (lk + (row >> 1)) & 3;
      bf[ni] = *(const short8*)(Bs + row * 64 + slot * 16);
    }
    mfma16(af, bf);
    __syncthreads();
  }

#pragma unroll
  for (int ni = 0; ni < 4; ++ni) {
    const int col = wc * 64 + ni * 16 + lr;
    const float bias = b1[col];
#pragma unroll
    for (int mi = 0; mi < 4; ++mi)
#pragma unroll
      for (int r = 0; r < 4; ++r) {
        float x = acc[mi][ni][r] + bias;
        x = x > 0.f ? x : 0.f;
        const int row = wr * 64 + mi * 16 + lk * 4 + r;
        *(unsigned short*)(Hs + row * 512 + ((col >> 3) ^ (row & 7)) * 16 +
                           (col & 7) * 2) = f2b(x);
        acc[mi][ni][r] = 0.f;
      }
  }
  __syncthreads();

  for (int u = 0; u < 8; ++u) {
    stageB1(wt2p, u);
    __syncthreads();
    short8 af[4], bf[4];
#pragma unroll
    for (int mi = 0; mi < 4; ++mi) {
      const int row = wr * 64 + mi * 16 + lr;
      af[mi] = *(const short8*)(Hs + row * 512 +
                                ((((u << 2) + lk) ^ (row & 7)) << 4));
    }
#pragma unroll
    for (int ni = 0; ni < 4; ++ni) {
      const int row = wc * 64 + ni * 16 + lr;
      const int slot = (lk + (row >> 1)) & 3;
      bf[ni] = *(const short8*)(Bs + row * 64 + slot * 16);
    }
    mfma16(af, bf);
    __syncthreads();
  }

  float* outst = (float*)smem;
#pragma unroll
  for (int p = 0; p < 2; ++p) {
    __syncthreads();
    if (wr == p) {
#pragma unroll
      for (int ni = 0; ni < 4; ++ni) {
        const int col = wc * 64 + ni * 16 + lr;
        const float bias = b2[col];
#pragma unroll
        for (int mi = 0; mi < 4; ++mi)
#pragma unroll
          for (int r = 0; r < 4; ++r)
            outst[(mi * 16 + lk * 4 + r) * LDO + col] = acc[mi][ni][r] + bias;
      }
    }
    __syncthreads();
#pragma unroll
    for (int it = 0; it < 8; ++it) {
      const int idx = it * 2048 + t * 4;
      const int lrow = idx >> 8;
      const int cc = idx & 255;
      const int grow = ebase + p * 64 + lrow;
      if (grow < E)
        *(float4*)(out + (size_t)grow * 256 + cc) =
            *(const float4*)(outst + lrow * LDO + cc);
    }
  }
}

extern "C" void kernel_launch(void* const* d_in, const int* in_sizes, int n_in,
                              void* d_out, int out_size, void* d_ws, size_t ws_size,
                              hipStream_t stream) {
  const float* xnode = (const float*)d_in[0];
  const float* xedge = (const float*)d_in[1];
  const int* eidx = (const int*)d_in[2];
  const float* W1 = (const float*)d_in[3];
  const float* b1 = (const float*)d_in[4];
  const float* W2 = (const float*)d_in[5];
  const float* b2 = (const float*)d_in[6];
  float* out = (float*)d_out;

  const int NN = in_sizes[0] / 256;   // 50000
  const int E = in_sizes[1] / 256;    // 300000

  char* ws = (char*)d_ws;
  unsigned short* wt1p = (unsigned short*)ws;                   // 24 x 16KB
  unsigned short* wt2p = (unsigned short*)(ws + 24 * 16384);    //  8 x 16KB
  unsigned short* nodeb = (unsigned short*)(ws + 32 * 16384);   // NN*512B
  const size_t need_full = (size_t)32 * 16384 + (size_t)NN * 512;

  prep_w_kernel<<<(24 * 8192 + 255) / 256, 256, 0, stream>>>(W1, wt1p, 24 * 8192);
  prep_w_kernel<<<(8 * 8192 + 255) / 256, 256, 0, stream>>>(W2, wt2p, 8 * 8192);

  const int grid = (E + 127) / 128;
  if (ws_size >= need_full) {
    const int n4 = NN * 64;
    conv_bf16_kernel<<<(n4 + 255) / 256, 256, 0, stream>>>(xnode, nodeb, n4);
    edge_mlp_full<<<grid, 512, 0, stream>>>(xedge, eidx, nodeb, wt1p, b1,
                                            wt2p, b2, out, E);
  } else {
    edge_mlp_simple<<<grid, 512, 0, stream>>>(xnode, xedge, eidx, wt1p, b1,
                                              wt2p, b2, out, E);
  }
}